// Round 3
// baseline (681.863 us; speedup 1.0000x reference)
//
#include <hip/hip_runtime.h>

#define BATCH 16384
#define NNODE 23
#define NF    16
#define HID   128
#define MROWS (BATCH * NNODE)   // 376832
#define MBLK  (MROWS / 16)      // 23552 (exact)
#define GCN_GRID (BATCH / 4)    // 4096
#define PREP_BLKS 24            // 12 per weight matrix
#define WELEM (3 * HID * HID)   // 49152 elements per weight matrix

typedef unsigned short u16;
typedef unsigned int   u32;
typedef __attribute__((ext_vector_type(8))) short s16x8;  // 8 bf16
typedef __attribute__((ext_vector_type(4))) float f32x4;

__device__ __forceinline__ float bf2f(u16 v) {
    union { u32 i; float f; } u; u.i = ((u32)v) << 16; return u.f;
}
__device__ __forceinline__ u16 f2bf(float f) {
    union { float f; u32 i; } u; u.f = f;
    return (u16)((u.i + 0x7FFFu + ((u.i >> 16) & 1u)) >> 16);  // RNE
}
// HW packed f32->bf16 (RNE), 2 floats -> 1 u32 {lo16=a, hi16=b}
__device__ __forceinline__ u32 cvtpk(float a, float b) {
    u32 r; asm("v_cvt_pk_bf16_f32 %0, %1, %2" : "=v"(r) : "v"(a), "v"(b));
    return r;
}
__device__ __forceinline__ float sigm(float x) { return 1.0f / (1.0f + __expf(-x)); }
__device__ __forceinline__ float tanh_fast(float x) {
    float e = __expf(2.0f * x);
    return 1.0f - 2.0f / (e + 1.0f);
}
__device__ __forceinline__ float lds1(const void* base, size_t i, int f32) {
    return f32 ? ((const float*)base)[i] : bf2f(((const u16*)base)[i]);
}
__device__ __forceinline__ void st1(void* base, size_t i, int f32, float v) {
    if (f32) ((float*)base)[i] = v;
    else     ((u16*)base)[i]   = f2bf(v);
}
__device__ __forceinline__ s16x8 ldfrag(const void* base, size_t elem_off, int f32) {
    if (f32) {
        const float* f = (const float*)base + elem_off;
        const float4 a = *(const float4*)f;
        const float4 b = *(const float4*)(f + 4);
        return (s16x8){(short)f2bf(a.x), (short)f2bf(a.y), (short)f2bf(a.z), (short)f2bf(a.w),
                       (short)f2bf(b.x), (short)f2bf(b.y), (short)f2bf(b.z), (short)f2bf(b.w)};
    }
    return *(const s16x8*)((const u16*)base + elem_off);
}
__device__ __forceinline__ s16x8 pack_bf16(float4 a, float4 b) {
    union { u32 w[4]; s16x8 v; } u;
    u.w[0] = cvtpk(a.x, a.y); u.w[1] = cvtpk(a.z, a.w);
    u.w[2] = cvtpk(b.x, b.y); u.w[3] = cvtpk(b.z, b.w);
    return u.v;
}
// Per-wave dtype sniff: bf16 exponents land in [0x66,0x90] -> ~0 wild; fp32
// misread makes even u16s mantissa slices -> ~40% wild. Threshold 8/64.
__device__ __forceinline__ int wave_sniff(const void* p) {
    const u16 v = ((const u16*)p)[threadIdx.x & 63];
    const u32 e = (v >> 7) & 0xFFu;
    const int wild = (e != 0u && (e < 0x66u || e > 0x90u)) ? 1 : 0;
    return __popcll(__ballot(wild)) > 8 ? 1 : 0;
}

// ---------------------------------------------------------------------------
// GCN (+ weight prep): blocks [0, GCN_GRID) compute
//   spatial = relu( (adj @ x) @ Wg^T + rowsum(adj)*bg )   (one batch per wave)
// blocks [GCN_GRID, GCN_GRID+24) convert W_ih / W_hh to bf16 in workspace.
// (unchanged from round 2 — isolating the gru register fix)
// ---------------------------------------------------------------------------
#define ADJ_OFF 0
#define X_OFF   532
#define TF_OFF  900
#define RS_OFF  1268
#define WSZ     1292

__global__ __launch_bounds__(256, 4) void gcn_kernel(
    const void* __restrict__ x, const void* __restrict__ adj,
    const void* __restrict__ Wg, const void* __restrict__ bg,
    u16* __restrict__ spatial,
    const void* __restrict__ W_ih, const void* __restrict__ W_hh,
    u16* __restrict__ wih_b, u16* __restrict__ whh_b)
{
    __shared__ float sc[4 * WSZ];   // 20.7 KB, per-wave scratch

    if (blockIdx.x >= GCN_GRID) {
        if (!wih_b) return;
        const int pb = blockIdx.x - GCN_GRID;        // 0..23
        const void* src = (pb < 12) ? W_ih : W_hh;
        u16*        dst = (pb < 12) ? wih_b : whh_b;
        const int   p   = (pb < 12) ? pb : pb - 12;  // 0..11
        const int wf32  = wave_sniff(src);
        const int base  = (p * 256 + (int)threadIdx.x) * 16;  // 16 elems/thread
        u32* d = (u32*)(dst + base);
        if (wf32) {
            const float4* s = (const float4*)((const float*)src + base);
            const float4 v0 = s[0], v1 = s[1], v2 = s[2], v3 = s[3];
            d[0] = cvtpk(v0.x, v0.y); d[1] = cvtpk(v0.z, v0.w);
            d[2] = cvtpk(v1.x, v1.y); d[3] = cvtpk(v1.z, v1.w);
            d[4] = cvtpk(v2.x, v2.y); d[5] = cvtpk(v2.z, v2.w);
            d[6] = cvtpk(v3.x, v3.y); d[7] = cvtpk(v3.z, v3.w);
        } else {
            const u32* s = (const u32*)((const u16*)src + base);
#pragma unroll
            for (int i = 0; i < 8; i++) d[i] = s[i];
        }
        return;
    }

    const int f32 = wave_sniff(x);
    const int l   = threadIdx.x & 63;
    const int wid = threadIdx.x >> 6;
    const int b   = blockIdx.x * 4 + wid;

    float* adjf = &sc[wid * WSZ + ADJ_OFF];
    float* xf   = &sc[wid * WSZ + X_OFF];
    float* tf   = &sc[wid * WSZ + TF_OFF];
    float* rs   = &sc[wid * WSZ + RS_OFF];

    const int c0 = 2 * l;
    float wa[NF], wb[NF];
#pragma unroll
    for (int f = 0; f < NF; f++) {
        wa[f] = lds1(Wg, (size_t)c0 * NF + f, f32);
        wb[f] = lds1(Wg, (size_t)(c0 + 1) * NF + f, f32);
    }
    const float bga = lds1(bg, c0, f32);
    const float bgb = lds1(bg, c0 + 1, f32);

    if (f32) {
        const float* ap = (const float*)adj + (size_t)b * (NNODE * NNODE);
        for (int i = l; i < NNODE * NNODE; i += 64) adjf[i] = ap[i];
        const float4* xp = (const float4*)((const float*)x + (size_t)b * (NNODE * NF));
        for (int i = l; i < (NNODE * NF) / 4; i += 64) *(float4*)&xf[i * 4] = xp[i];
    } else {
        const u16* ap = (const u16*)adj + (size_t)b * (NNODE * NNODE);
        for (int i = l; i < NNODE * NNODE; i += 64) adjf[i] = bf2f(ap[i]);
        const u16* xp = (const u16*)x + (size_t)b * (NNODE * NF);
        if (l < (NNODE * NF) / 8) {
            s16x8 v = *(const s16x8*)(xp + l * 8);
            float4 t0 = {bf2f((u16)v[0]), bf2f((u16)v[1]), bf2f((u16)v[2]), bf2f((u16)v[3])};
            float4 t1 = {bf2f((u16)v[4]), bf2f((u16)v[5]), bf2f((u16)v[6]), bf2f((u16)v[7])};
            *(float4*)&xf[l * 8]     = t0;
            *(float4*)&xf[l * 8 + 4] = t1;
        }
    }
    __syncthreads();

    if (l < 2 * NNODE) {
        const int n  = l >> 1;
        const int f0 = (l & 1) * 8;
        float4 a0 = {0, 0, 0, 0}, a1 = {0, 0, 0, 0};
        float rsum = 0.f;
#pragma unroll
        for (int m = 0; m < NNODE; m++) {
            const float  a  = adjf[n * NNODE + m];
            const float4 x0 = *(const float4*)&xf[m * NF + f0];
            const float4 x1 = *(const float4*)&xf[m * NF + f0 + 4];
            a0.x += a * x0.x; a0.y += a * x0.y; a0.z += a * x0.z; a0.w += a * x0.w;
            a1.x += a * x1.x; a1.y += a * x1.y; a1.z += a * x1.z; a1.w += a * x1.w;
            rsum += a;
        }
        *(float4*)&tf[n * NF + f0]     = a0;
        *(float4*)&tf[n * NF + f0 + 4] = a1;
        if ((l & 1) == 0) rs[n] = rsum;
    }
    __syncthreads();

    const u32 sbase = (u32)b * (NNODE * HID);
    u32* sp = (u32*)spatial;
    for (int n = 0; n < NNODE; n++) {
        const float4 t0 = *(const float4*)&tf[n * NF];
        const float4 t1 = *(const float4*)&tf[n * NF + 4];
        const float4 t2 = *(const float4*)&tf[n * NF + 8];
        const float4 t3 = *(const float4*)&tf[n * NF + 12];
        const float  rv = rs[n];
        float a0 = rv * bga;
        float a1 = rv * bgb;
        a0 += t0.x*wa[0]  + t0.y*wa[1]  + t0.z*wa[2]  + t0.w*wa[3];
        a0 += t1.x*wa[4]  + t1.y*wa[5]  + t1.z*wa[6]  + t1.w*wa[7];
        a0 += t2.x*wa[8]  + t2.y*wa[9]  + t2.z*wa[10] + t2.w*wa[11];
        a0 += t3.x*wa[12] + t3.y*wa[13] + t3.z*wa[14] + t3.w*wa[15];
        a1 += t0.x*wb[0]  + t0.y*wb[1]  + t0.z*wb[2]  + t0.w*wb[3];
        a1 += t1.x*wb[4]  + t1.y*wb[5]  + t1.z*wb[6]  + t1.w*wb[7];
        a1 += t2.x*wb[8]  + t2.y*wb[9]  + t2.z*wb[10] + t2.w*wb[11];
        a1 += t3.x*wb[12] + t3.y*wb[13] + t3.z*wb[14] + t3.w*wb[15];
        sp[(sbase + (u32)n * HID + (u32)c0) >> 1] =
            cvtpk(fmaxf(a0, 0.f), fmaxf(a1, 0.f));
    }
}

// ---------------------------------------------------------------------------
// GRU fast path: decoupled waves, wave = (tile rb, colgroup jt).
// KEY FIX vs round 2: the 24 persistent B fragments (and 4 gate biases) are
// pinned via empty asm with "+v" — opaque defs the compiler cannot
// rematerialize, forcing them to stay live in VGPRs across the whole loop.
// Budget: ~230 regs < 256 allowed by __launch_bounds__(256,2); 2 waves/SIMD.
// ---------------------------------------------------------------------------
#define LOAD_A(S, H, RB) do {                                                  \
    const size_t ar_ = (size_t)((RB) * 16 + n16) * HID + kob;                  \
    _Pragma("unroll")                                                          \
    for (int kt = 0; kt < 4; kt++)                                             \
        S[kt] = *(const s16x8*)&spatial[ar_ + kt * 32];                        \
    if (f32) {                                                                 \
        const float* hp4 = (const float*)h_prev + ar_;                         \
        _Pragma("unroll")                                                      \
        for (int kt = 0; kt < 4; kt++) {                                       \
            H[2*kt]   = *(const float4*)(hp4 + kt * 32);                       \
            H[2*kt+1] = *(const float4*)(hp4 + kt * 32 + 4);                   \
        }                                                                      \
    } else {                                                                   \
        const u16* hb = (const u16*)h_prev + ar_;                              \
        _Pragma("unroll")                                                      \
        for (int kt = 0; kt < 4; kt++)                                         \
            H[2*kt] = *(const float4*)(hb + kt * 32);                          \
    }                                                                          \
} while (0)

#define COMPUTE(S, H, RB) do {                                                 \
    const size_t o_ = (size_t)((RB) * 16 + quad * 4) * HID + c;                \
    float hp_[4];  /* L1-hot: rows this wave's block just loaded for H */      \
    _Pragma("unroll")                                                          \
    for (int r_ = 0; r_ < 4; r_++)                                             \
        hp_[r_] = lds1(h_prev, o_ + (size_t)r_ * HID, f32);                    \
    s16x8 Ah[4];                                                               \
    if (f32) {                                                                 \
        _Pragma("unroll")                                                      \
        for (int kt = 0; kt < 4; kt++) Ah[kt] = pack_bf16(H[2*kt], H[2*kt+1]); \
    } else {                                                                   \
        _Pragma("unroll")                                                      \
        for (int kt = 0; kt < 4; kt++) {                                       \
            union { float4 f; s16x8 s; } u_; u_.f = H[2*kt]; Ah[kt] = u_.s;    \
        }                                                                      \
    }                                                                          \
    f32x4 accr = {0,0,0,0}, accz = {0,0,0,0};                                  \
    f32x4 accni = {0,0,0,0}, accnh = {0,0,0,0};                                \
    _Pragma("unroll")                                                          \
    for (int kt = 0; kt < 4; kt++) {                                           \
        accr  = __builtin_amdgcn_mfma_f32_16x16x32_bf16(S[kt],  Bir[kt], accr, 0,0,0); \
        accr  = __builtin_amdgcn_mfma_f32_16x16x32_bf16(Ah[kt], Bhr[kt], accr, 0,0,0); \
        accz  = __builtin_amdgcn_mfma_f32_16x16x32_bf16(S[kt],  Biz[kt], accz, 0,0,0); \
        accz  = __builtin_amdgcn_mfma_f32_16x16x32_bf16(Ah[kt], Bhz[kt], accz, 0,0,0); \
        accni = __builtin_amdgcn_mfma_f32_16x16x32_bf16(S[kt],  Bin[kt], accni,0,0,0); \
        accnh = __builtin_amdgcn_mfma_f32_16x16x32_bf16(Ah[kt], Bhn[kt], accnh,0,0,0); \
    }                                                                          \
    _Pragma("unroll")                                                          \
    for (int reg = 0; reg < 4; reg++) {                                        \
        const float r_ = sigm(accr[reg] + br);                                 \
        const float z_ = sigm(accz[reg] + bz);                                 \
        const float n_ = tanh_fast(accni[reg] + bin_ + r_ * (accnh[reg] + bhn)); \
        st1(out, o_ + (size_t)reg * HID, f32, (1.0f - z_) * n_ + z_ * hp_[reg]); \
    }                                                                          \
} while (0)

__global__ __launch_bounds__(256, 2) void gru_fast(
    const u16* __restrict__ spatial, const void* __restrict__ h_prev,
    const u16* __restrict__ wih_b, const u16* __restrict__ whh_b,
    const void* __restrict__ b_ih, const void* __restrict__ b_hh,
    void* __restrict__ out)
{
    const int f32  = wave_sniff(h_prev);
    const int lane = threadIdx.x & 63;
    const int gw   = blockIdx.x * 4 + (threadIdx.x >> 6);
    const int jt   = gw & 7;             // colgroup: fixed per wave
    const int n16  = lane & 15;
    const int quad = lane >> 4;
    const int c    = jt * 16 + n16;      // gate column 0..127
    const int kob  = quad * 8;

    // persistent B fragments: plain bf16 loads from pre-converted weights
    s16x8 Bir[4], Biz[4], Bin[4], Bhr[4], Bhz[4], Bhn[4];
#pragma unroll
    for (int kt = 0; kt < 4; kt++) {
        const int ko = kt * 32 + kob;
        Bir[kt] = *(const s16x8*)&wih_b[(size_t)(c)       * HID + ko];
        Biz[kt] = *(const s16x8*)&wih_b[(size_t)(128 + c) * HID + ko];
        Bin[kt] = *(const s16x8*)&wih_b[(size_t)(256 + c) * HID + ko];
        Bhr[kt] = *(const s16x8*)&whh_b[(size_t)(c)       * HID + ko];
        Bhz[kt] = *(const s16x8*)&whh_b[(size_t)(128 + c) * HID + ko];
        Bhn[kt] = *(const s16x8*)&whh_b[(size_t)(256 + c) * HID + ko];
    }
    float br   = lds1(b_ih, c, f32)       + lds1(b_hh, c, f32);
    float bz   = lds1(b_ih, 128 + c, f32) + lds1(b_hh, 128 + c, f32);
    float bin_ = lds1(b_ih, 256 + c, f32);
    float bhn  = lds1(b_hh, 256 + c, f32);

    // --- opacity pins: forbid rematerialization of loop-invariant state ---
#pragma unroll
    for (int kt = 0; kt < 4; kt++) {
        asm("" : "+v"(Bir[kt])); asm("" : "+v"(Biz[kt])); asm("" : "+v"(Bin[kt]));
        asm("" : "+v"(Bhr[kt])); asm("" : "+v"(Bhz[kt])); asm("" : "+v"(Bhn[kt]));
    }
    asm("" : "+v"(br)); asm("" : "+v"(bz)); asm("" : "+v"(bin_)); asm("" : "+v"(bhn));

    const int stride = (int)(gridDim.x * 4) >> 3;   // row-wave count per jt
    int rb = gw >> 3;
    if (rb >= MBLK) return;

    s16x8 S0[4], S1[4];
    float4 H0[8], H1[8];

    LOAD_A(S0, H0, rb);
    int nxt = rb + stride;
    while (true) {
        if (nxt < MBLK) LOAD_A(S1, H1, nxt);    // prefetch depth 1
        COMPUTE(S0, H0, rb);
        rb = nxt; nxt += stride;
        if (rb >= MBLK) break;
        if (nxt < MBLK) LOAD_A(S0, H0, nxt);
        COMPUTE(S1, H1, rb);
        rb = nxt; nxt += stride;
        if (rb >= MBLK) break;
    }
}

// ---------------------------------------------------------------------------
// GRU safe path (workspace too small): unchanged.
// ---------------------------------------------------------------------------
__global__ __launch_bounds__(512, 2) void gru_safe(
    const u16* __restrict__ spatial, const void* __restrict__ h_prev,
    const void* __restrict__ W_ih, const void* __restrict__ W_hh,
    const void* __restrict__ b_ih, const void* __restrict__ b_hh,
    void* __restrict__ out)
{
    const int f32  = wave_sniff(h_prev);
    const int lane = threadIdx.x & 63;
    const int jt   = threadIdx.x >> 6;
    const int n16  = lane & 15;
    const int quad = lane >> 4;
    const int c    = jt * 16 + n16;
    const int kob  = quad * 8;

    s16x8 Bir[4], Biz[4], Bin[4], Bhr[4], Bhz[4], Bhn[4];
#pragma unroll
    for (int kt = 0; kt < 4; kt++) {
        const int ko = kt * 32 + kob;
        Bir[kt] = ldfrag(W_ih, (size_t)(c)       * HID + ko, f32);
        Biz[kt] = ldfrag(W_ih, (size_t)(128 + c) * HID + ko, f32);
        Bin[kt] = ldfrag(W_ih, (size_t)(256 + c) * HID + ko, f32);
        Bhr[kt] = ldfrag(W_hh, (size_t)(c)       * HID + ko, f32);
        Bhz[kt] = ldfrag(W_hh, (size_t)(128 + c) * HID + ko, f32);
        Bhn[kt] = ldfrag(W_hh, (size_t)(256 + c) * HID + ko, f32);
    }
    const float br   = lds1(b_ih, c, f32)       + lds1(b_hh, c, f32);
    const float bz   = lds1(b_ih, 128 + c, f32) + lds1(b_hh, 128 + c, f32);
    const float bin_ = lds1(b_ih, 256 + c, f32);
    const float bhn  = lds1(b_hh, 256 + c, f32);

    for (int rb = blockIdx.x; rb < MBLK; rb += gridDim.x) {
        const size_t ar = (size_t)(rb * 16 + n16) * HID + kob;
        s16x8 As[4], Ah[4];
#pragma unroll
        for (int kt = 0; kt < 4; kt++) {
            As[kt] = *(const s16x8*)&spatial[ar + kt * 32];
            Ah[kt] = ldfrag(h_prev, ar + kt * 32, f32);
        }

        f32x4 air = {0,0,0,0}, aiz = {0,0,0,0}, ain = {0,0,0,0};
        f32x4 ahr = {0,0,0,0}, ahz = {0,0,0,0}, ahn = {0,0,0,0};
#pragma unroll
        for (int kt = 0; kt < 4; kt++) {
            air = __builtin_amdgcn_mfma_f32_16x16x32_bf16(As[kt], Bir[kt], air, 0, 0, 0);
            ahr = __builtin_amdgcn_mfma_f32_16x16x32_bf16(Ah[kt], Bhr[kt], ahr, 0, 0, 0);
            aiz = __builtin_amdgcn_mfma_f32_16x16x32_bf16(As[kt], Biz[kt], aiz, 0, 0, 0);
            ahz = __builtin_amdgcn_mfma_f32_16x16x32_bf16(Ah[kt], Bhz[kt], ahz, 0, 0, 0);
            ain = __builtin_amdgcn_mfma_f32_16x16x32_bf16(As[kt], Bin[kt], ain, 0, 0, 0);
            ahn = __builtin_amdgcn_mfma_f32_16x16x32_bf16(Ah[kt], Bhn[kt], ahn, 0, 0, 0);
        }

        __syncthreads();   // all spatial reads of rows rb complete before writes

        const int row0 = rb * 16 + quad * 4;
#pragma unroll
        for (int reg = 0; reg < 4; reg++) {
            const size_t o = (size_t)(row0 + reg) * HID + c;
            const float r  = sigm(air[reg] + ahr[reg] + br);
            const float z  = sigm(aiz[reg] + ahz[reg] + bz);
            const float nn = tanh_fast(ain[reg] + bin_ + r * (ahn[reg] + bhn));
            const float hp = lds1(h_prev, o, f32);
            st1(out, o, f32, (1.0f - z) * nn + z * hp);
        }
    }
}

extern "C" void kernel_launch(void* const* d_in, const int* in_sizes, int n_in,
                              void* d_out, int out_size, void* d_ws, size_t ws_size,
                              hipStream_t stream) {
    const void* x      = d_in[0];
    const void* adj    = d_in[1];
    const void* h_prev = d_in[2];
    const void* W_gcn  = d_in[3];
    const void* b_gcn  = d_in[4];
    const void* W_ih   = d_in[5];
    const void* W_hh   = d_in[6];
    const void* b_ih   = d_in[7];
    const void* b_hh   = d_in[8];

    const size_t need   = (size_t)MROWS * HID * sizeof(u16);   // 92 MB bf16 spatial
    const size_t wbytes = (size_t)WELEM * sizeof(u16);         // 96 KB per matrix
    const bool have_ws = (ws_size >= need);
    const bool have_w  = (ws_size >= need + 2 * wbytes);

    u16* spatial = have_ws ? (u16*)d_ws : (u16*)d_out;
    u16* wih_b   = have_w ? (u16*)((char*)d_ws + need) : nullptr;
    u16* whh_b   = have_w ? (u16*)((char*)d_ws + need + wbytes) : nullptr;

    gcn_kernel<<<GCN_GRID + (have_w ? PREP_BLKS : 0), 256, 0, stream>>>(
        x, adj, W_gcn, b_gcn, spatial, W_ih, W_hh, wih_b, whh_b);

    if (have_w)
        gru_fast<<<2048, 256, 0, stream>>>(spatial, h_prev, wih_b, whh_b,
                                           b_ih, b_hh, d_out);
    else
        gru_safe<<<2048, 512, 0, stream>>>(spatial, h_prev, W_ih, W_hh,
                                           b_ih, b_hh, d_out);
}

// Round 4
// 661.435 us; speedup vs baseline: 1.0309x; 1.0309x over previous
//
#include <hip/hip_runtime.h>

#define BATCH 16384
#define NNODE 23
#define NF    16
#define HID   128
#define MROWS (BATCH * NNODE)   // 376832
#define MBLK  (MROWS / 16)      // 23552 (exact)
#define GCN_BLOCKS 2048         // 4 waves * 2 batches each = 16384
#define PREP_BLKS 24            // 12 per weight matrix
#define WELEM (3 * HID * HID)   // 49152 elements per weight matrix

typedef unsigned short u16;
typedef unsigned int   u32;
typedef __attribute__((ext_vector_type(8))) short s16x8;  // 8 bf16
typedef __attribute__((ext_vector_type(4))) float f32x4;

__device__ __forceinline__ float bf2f(u16 v) {
    union { u32 i; float f; } u; u.i = ((u32)v) << 16; return u.f;
}
__device__ __forceinline__ u16 f2bf(float f) {
    union { float f; u32 i; } u; u.f = f;
    return (u16)((u.i + 0x7FFFu + ((u.i >> 16) & 1u)) >> 16);  // RNE
}
// HW packed f32->bf16 (RNE), 2 floats -> 1 u32 {lo16=a, hi16=b}
__device__ __forceinline__ u32 cvtpk(float a, float b) {
    u32 r; asm("v_cvt_pk_bf16_f32 %0, %1, %2" : "=v"(r) : "v"(a), "v"(b));
    return r;
}
__device__ __forceinline__ float sigm(float x) { return 1.0f / (1.0f + __expf(-x)); }
__device__ __forceinline__ float tanh_fast(float x) {
    float e = __expf(2.0f * x);
    return 1.0f - 2.0f / (e + 1.0f);
}
__device__ __forceinline__ float lds1(const void* base, size_t i, int f32) {
    return f32 ? ((const float*)base)[i] : bf2f(((const u16*)base)[i]);
}
__device__ __forceinline__ void st1(void* base, size_t i, int f32, float v) {
    if (f32) ((float*)base)[i] = v;
    else     ((u16*)base)[i]   = f2bf(v);
}
__device__ __forceinline__ s16x8 ldfrag(const void* base, size_t elem_off, int f32) {
    if (f32) {
        const float* f = (const float*)base + elem_off;
        const float4 a = *(const float4*)f;
        const float4 b = *(const float4*)(f + 4);
        return (s16x8){(short)f2bf(a.x), (short)f2bf(a.y), (short)f2bf(a.z), (short)f2bf(a.w),
                       (short)f2bf(b.x), (short)f2bf(b.y), (short)f2bf(b.z), (short)f2bf(b.w)};
    }
    return *(const s16x8*)((const u16*)base + elem_off);
}
__device__ __forceinline__ s16x8 pack_bf16(float4 a, float4 b) {
    union { u32 w[4]; s16x8 v; } u;
    u.w[0] = cvtpk(a.x, a.y); u.w[1] = cvtpk(a.z, a.w);
    u.w[2] = cvtpk(b.x, b.y); u.w[3] = cvtpk(b.z, b.w);
    return u.v;
}
// Per-wave dtype sniff: bf16 exponents land in [0x66,0x90] -> ~0 wild; fp32
// misread makes even u16s mantissa slices -> ~40% wild. Threshold 8/64.
__device__ __forceinline__ int wave_sniff(const void* p) {
    const u16 v = ((const u16*)p)[threadIdx.x & 63];
    const u32 e = (v >> 7) & 0xFFu;
    const int wild = (e != 0u && (e < 0x66u || e > 0x90u)) ? 1 : 0;
    return __popcll(__ballot(wild)) > 8 ? 1 : 0;
}

// ---------------------------------------------------------------------------
// GCN v2: TWO batches per wave with fully interleaved (independent) chains —
// the ILP covers LDS/global latency that the one-batch version exposed.
// blocks [0, GCN_BLOCKS): 4 waves x 2 batches; blocks [GCN_BLOCKS, +24):
// convert W_ih/W_hh to bf16 in workspace.
// Per-wave LDS: 2 slots of {adj 529, x 368, tf 368, rs 23} -> 1296 f/slot.
// ---------------------------------------------------------------------------
#define S_ADJ 0
#define S_X   532
#define S_TF  900
#define S_RS  1268
#define SLOT  1296              // floats per batch slot (16B-aligned)

__global__ __launch_bounds__(256, 3) void gcn_kernel(
    const void* __restrict__ x, const void* __restrict__ adj,
    const void* __restrict__ Wg, const void* __restrict__ bg,
    u16* __restrict__ spatial,
    const void* __restrict__ W_ih, const void* __restrict__ W_hh,
    u16* __restrict__ wih_b, u16* __restrict__ whh_b)
{
    __shared__ float sc[4 * 2 * SLOT];   // 41.5 KB

    if (blockIdx.x >= GCN_BLOCKS) {
        if (!wih_b) return;
        const int pb = blockIdx.x - GCN_BLOCKS;      // 0..23
        const void* src = (pb < 12) ? W_ih : W_hh;
        u16*        dst = (pb < 12) ? wih_b : whh_b;
        const int   p   = (pb < 12) ? pb : pb - 12;  // 0..11
        const int wf32  = wave_sniff(src);
        const int base  = (p * 256 + (int)threadIdx.x) * 16;  // 16 elems/thread
        u32* d = (u32*)(dst + base);
        if (wf32) {
            const float4* s = (const float4*)((const float*)src + base);
            const float4 v0 = s[0], v1 = s[1], v2 = s[2], v3 = s[3];
            d[0] = cvtpk(v0.x, v0.y); d[1] = cvtpk(v0.z, v0.w);
            d[2] = cvtpk(v1.x, v1.y); d[3] = cvtpk(v1.z, v1.w);
            d[4] = cvtpk(v2.x, v2.y); d[5] = cvtpk(v2.z, v2.w);
            d[6] = cvtpk(v3.x, v3.y); d[7] = cvtpk(v3.z, v3.w);
        } else {
            const u32* s = (const u32*)((const u16*)src + base);
#pragma unroll
            for (int i = 0; i < 8; i++) d[i] = s[i];
        }
        return;
    }

    const int f32 = wave_sniff(x);
    const int l   = threadIdx.x & 63;
    const int wid = threadIdx.x >> 6;
    const int b0  = (blockIdx.x * 4 + wid) * 2;   // batches b0, b0+1

    float* adj0 = &sc[wid * 2 * SLOT + S_ADJ];
    float* xf0  = &sc[wid * 2 * SLOT + S_X];
    float* tf0  = &sc[wid * 2 * SLOT + S_TF];
    float* rs0  = &sc[wid * 2 * SLOT + S_RS];
    float* adj1 = adj0 + SLOT;
    float* xf1  = xf0 + SLOT;
    float* tf1  = tf0 + SLOT;
    float* rs1  = rs0 + SLOT;

    // persistent per-lane weights: output cols c0, c0+1
    const int c0 = 2 * l;
    float wa[NF], wb[NF];
#pragma unroll
    for (int f = 0; f < NF; f++) {
        wa[f] = lds1(Wg, (size_t)c0 * NF + f, f32);
        wb[f] = lds1(Wg, (size_t)(c0 + 1) * NF + f, f32);
    }
    const float bga = lds1(bg, c0, f32);
    const float bgb = lds1(bg, c0 + 1, f32);

    // ---- stage0: both batches' adj & x to LDS (interleaved streams) ----
    if (f32) {
        const float* ap0 = (const float*)adj + (size_t)b0 * (NNODE * NNODE);
        const float* ap1 = ap0 + NNODE * NNODE;
        for (int i = l; i < NNODE * NNODE; i += 64) {
            adj0[i] = ap0[i];
            adj1[i] = ap1[i];
        }
        const float4* xp0 = (const float4*)((const float*)x + (size_t)b0 * (NNODE * NF));
        const float4* xp1 = xp0 + (NNODE * NF) / 4;
        for (int i = l; i < (NNODE * NF) / 4; i += 64) {
            *(float4*)&xf0[i * 4] = xp0[i];
            *(float4*)&xf1[i * 4] = xp1[i];
        }
    } else {
        const u16* ap0 = (const u16*)adj + (size_t)b0 * (NNODE * NNODE);
        const u16* ap1 = ap0 + NNODE * NNODE;
        for (int i = l; i < NNODE * NNODE; i += 64) {
            adj0[i] = bf2f(ap0[i]);
            adj1[i] = bf2f(ap1[i]);
        }
        const u16* xp0 = (const u16*)x + (size_t)b0 * (NNODE * NF);
        const u16* xp1 = xp0 + NNODE * NF;
        if (l < (NNODE * NF) / 8) {
            s16x8 v0 = *(const s16x8*)(xp0 + l * 8);
            s16x8 v1 = *(const s16x8*)(xp1 + l * 8);
#pragma unroll
            for (int j = 0; j < 8; j++) {
                xf0[l * 8 + j] = bf2f((u16)v0[j]);
                xf1[l * 8 + j] = bf2f((u16)v1[j]);
            }
        }
    }
    __syncthreads();

    // ---- stage1: tf = adj @ x (+ rowsum), both batches interleaved ----
    if (l < 2 * NNODE) {                 // 46 lanes, 2 chains each
        const int n  = l >> 1;
        const int f0 = (l & 1) * 8;
        float4 p00 = {0,0,0,0}, p01 = {0,0,0,0};
        float4 p10 = {0,0,0,0}, p11 = {0,0,0,0};
        float r0 = 0.f, r1 = 0.f;
#pragma unroll
        for (int m = 0; m < NNODE; m++) {
            const float  a0 = adj0[n * NNODE + m];
            const float  a1 = adj1[n * NNODE + m];
            const float4 xa = *(const float4*)&xf0[m * NF + f0];
            const float4 xb = *(const float4*)&xf0[m * NF + f0 + 4];
            const float4 xc = *(const float4*)&xf1[m * NF + f0];
            const float4 xd = *(const float4*)&xf1[m * NF + f0 + 4];
            p00.x += a0 * xa.x; p00.y += a0 * xa.y; p00.z += a0 * xa.z; p00.w += a0 * xa.w;
            p01.x += a0 * xb.x; p01.y += a0 * xb.y; p01.z += a0 * xb.z; p01.w += a0 * xb.w;
            p10.x += a1 * xc.x; p10.y += a1 * xc.y; p10.z += a1 * xc.z; p10.w += a1 * xc.w;
            p11.x += a1 * xd.x; p11.y += a1 * xd.y; p11.z += a1 * xd.z; p11.w += a1 * xd.w;
            r0 += a0; r1 += a1;
        }
        *(float4*)&tf0[n * NF + f0]     = p00;
        *(float4*)&tf0[n * NF + f0 + 4] = p01;
        *(float4*)&tf1[n * NF + f0]     = p10;
        *(float4*)&tf1[n * NF + f0 + 4] = p11;
        if ((l & 1) == 0) { rs0[n] = r0; rs1[n] = r1; }
    }
    __syncthreads();

    // ---- stage2: out[n][c0..c0+1] for both batches, 4 indep acc chains ----
    const u32 sb0 = (u32)b0 * (NNODE * HID);
    const u32 sb1 = sb0 + NNODE * HID;
    u32* sp = (u32*)spatial;
#pragma unroll 4
    for (int n = 0; n < NNODE; n++) {
        const float4 t00 = *(const float4*)&tf0[n * NF];
        const float4 t01 = *(const float4*)&tf0[n * NF + 4];
        const float4 t02 = *(const float4*)&tf0[n * NF + 8];
        const float4 t03 = *(const float4*)&tf0[n * NF + 12];
        const float4 t10 = *(const float4*)&tf1[n * NF];
        const float4 t11 = *(const float4*)&tf1[n * NF + 4];
        const float4 t12 = *(const float4*)&tf1[n * NF + 8];
        const float4 t13 = *(const float4*)&tf1[n * NF + 12];
        const float  rv0 = rs0[n], rv1 = rs1[n];
        float a00 = rv0 * bga, a01 = rv0 * bgb;
        float a10 = rv1 * bga, a11 = rv1 * bgb;
        a00 += t00.x*wa[0]  + t00.y*wa[1]  + t00.z*wa[2]  + t00.w*wa[3];
        a00 += t01.x*wa[4]  + t01.y*wa[5]  + t01.z*wa[6]  + t01.w*wa[7];
        a00 += t02.x*wa[8]  + t02.y*wa[9]  + t02.z*wa[10] + t02.w*wa[11];
        a00 += t03.x*wa[12] + t03.y*wa[13] + t03.z*wa[14] + t03.w*wa[15];
        a01 += t00.x*wb[0]  + t00.y*wb[1]  + t00.z*wb[2]  + t00.w*wb[3];
        a01 += t01.x*wb[4]  + t01.y*wb[5]  + t01.z*wb[6]  + t01.w*wb[7];
        a01 += t02.x*wb[8]  + t02.y*wb[9]  + t02.z*wb[10] + t02.w*wb[11];
        a01 += t03.x*wb[12] + t03.y*wb[13] + t03.z*wb[14] + t03.w*wb[15];
        a10 += t10.x*wa[0]  + t10.y*wa[1]  + t10.z*wa[2]  + t10.w*wa[3];
        a10 += t11.x*wa[4]  + t11.y*wa[5]  + t11.z*wa[6]  + t11.w*wa[7];
        a10 += t12.x*wa[8]  + t12.y*wa[9]  + t12.z*wa[10] + t12.w*wa[11];
        a10 += t13.x*wa[12] + t13.y*wa[13] + t13.z*wa[14] + t13.w*wa[15];
        a11 += t10.x*wb[0]  + t10.y*wb[1]  + t10.z*wb[2]  + t10.w*wb[3];
        a11 += t11.x*wb[4]  + t11.y*wb[5]  + t11.z*wb[6]  + t11.w*wb[7];
        a11 += t12.x*wb[8]  + t12.y*wb[9]  + t12.z*wb[10] + t12.w*wb[11];
        a11 += t13.x*wb[12] + t13.y*wb[13] + t13.z*wb[14] + t13.w*wb[15];
        sp[(sb0 + (u32)n * HID + (u32)c0) >> 1] = cvtpk(fmaxf(a00, 0.f), fmaxf(a01, 0.f));
        sp[(sb1 + (u32)n * HID + (u32)c0) >> 1] = cvtpk(fmaxf(a10, 0.f), fmaxf(a11, 0.f));
    }
}

// ---------------------------------------------------------------------------
// GRU fast path: unchanged structure (parked); only 64-bit -> 32-bit
// addressing in the hot loop (all element offsets < 2^32).
// ---------------------------------------------------------------------------
#define LOAD_A(S, H, RB) do {                                                  \
    const u32 ar_ = (u32)((RB) * 16 + n16) * HID + kob;                        \
    _Pragma("unroll")                                                          \
    for (int kt = 0; kt < 4; kt++)                                             \
        S[kt] = *(const s16x8*)&spatial[ar_ + kt * 32];                        \
    if (f32) {                                                                 \
        const float* hp4 = (const float*)h_prev + ar_;                         \
        _Pragma("unroll")                                                      \
        for (int kt = 0; kt < 4; kt++) {                                       \
            H[2*kt]   = *(const float4*)(hp4 + kt * 32);                       \
            H[2*kt+1] = *(const float4*)(hp4 + kt * 32 + 4);                   \
        }                                                                      \
    } else {                                                                   \
        const u16* hb = (const u16*)h_prev + ar_;                              \
        _Pragma("unroll")                                                      \
        for (int kt = 0; kt < 4; kt++)                                         \
            H[2*kt] = *(const float4*)(hb + kt * 32);                          \
    }                                                                          \
} while (0)

#define COMPUTE(S, H, RB) do {                                                 \
    const u32 o_ = (u32)((RB) * 16 + quad * 4) * HID + c;                      \
    float hp_[4];  /* L1-hot: rows this wave just loaded for H */              \
    _Pragma("unroll")                                                          \
    for (int r_ = 0; r_ < 4; r_++)                                             \
        hp_[r_] = lds1(h_prev, o_ + (u32)r_ * HID, f32);                       \
    s16x8 Ah[4];                                                               \
    if (f32) {                                                                 \
        _Pragma("unroll")                                                      \
        for (int kt = 0; kt < 4; kt++) Ah[kt] = pack_bf16(H[2*kt], H[2*kt+1]); \
    } else {                                                                   \
        _Pragma("unroll")                                                      \
        for (int kt = 0; kt < 4; kt++) {                                       \
            union { float4 f; s16x8 s; } u_; u_.f = H[2*kt]; Ah[kt] = u_.s;    \
        }                                                                      \
    }                                                                          \
    f32x4 accr = {0,0,0,0}, accz = {0,0,0,0};                                  \
    f32x4 accni = {0,0,0,0}, accnh = {0,0,0,0};                                \
    _Pragma("unroll")                                                          \
    for (int kt = 0; kt < 4; kt++) {                                           \
        accr  = __builtin_amdgcn_mfma_f32_16x16x32_bf16(S[kt],  Bir[kt], accr, 0,0,0); \
        accr  = __builtin_amdgcn_mfma_f32_16x16x32_bf16(Ah[kt], Bhr[kt], accr, 0,0,0); \
        accz  = __builtin_amdgcn_mfma_f32_16x16x32_bf16(S[kt],  Biz[kt], accz, 0,0,0); \
        accz  = __builtin_amdgcn_mfma_f32_16x16x32_bf16(Ah[kt], Bhz[kt], accz, 0,0,0); \
        accni = __builtin_amdgcn_mfma_f32_16x16x32_bf16(S[kt],  Bin[kt], accni,0,0,0); \
        accnh = __builtin_amdgcn_mfma_f32_16x16x32_bf16(Ah[kt], Bhn[kt], accnh,0,0,0); \
    }                                                                          \
    _Pragma("unroll")                                                          \
    for (int reg = 0; reg < 4; reg++) {                                        \
        const float r_ = sigm(accr[reg] + br);                                 \
        const float z_ = sigm(accz[reg] + bz);                                 \
        const float n_ = tanh_fast(accni[reg] + bin_ + r_ * (accnh[reg] + bhn)); \
        st1(out, o_ + (u32)reg * HID, f32, (1.0f - z_) * n_ + z_ * hp_[reg]);  \
    }                                                                          \
} while (0)

__global__ __launch_bounds__(256, 2) void gru_fast(
    const u16* __restrict__ spatial, const void* __restrict__ h_prev,
    const u16* __restrict__ wih_b, const u16* __restrict__ whh_b,
    const void* __restrict__ b_ih, const void* __restrict__ b_hh,
    void* __restrict__ out)
{
    const int f32  = wave_sniff(h_prev);
    const int lane = threadIdx.x & 63;
    const int gw   = blockIdx.x * 4 + (threadIdx.x >> 6);
    const int jt   = gw & 7;             // colgroup: fixed per wave
    const int n16  = lane & 15;
    const int quad = lane >> 4;
    const int c    = jt * 16 + n16;      // gate column 0..127
    const int kob  = quad * 8;

    // persistent B fragments: plain bf16 loads from pre-converted weights
    s16x8 Bir[4], Biz[4], Bin[4], Bhr[4], Bhz[4], Bhn[4];
#pragma unroll
    for (int kt = 0; kt < 4; kt++) {
        const int ko = kt * 32 + kob;
        Bir[kt] = *(const s16x8*)&wih_b[(size_t)(c)       * HID + ko];
        Biz[kt] = *(const s16x8*)&wih_b[(size_t)(128 + c) * HID + ko];
        Bin[kt] = *(const s16x8*)&wih_b[(size_t)(256 + c) * HID + ko];
        Bhr[kt] = *(const s16x8*)&whh_b[(size_t)(c)       * HID + ko];
        Bhz[kt] = *(const s16x8*)&whh_b[(size_t)(128 + c) * HID + ko];
        Bhn[kt] = *(const s16x8*)&whh_b[(size_t)(256 + c) * HID + ko];
    }
    const float br   = lds1(b_ih, c, f32)       + lds1(b_hh, c, f32);
    const float bz   = lds1(b_ih, 128 + c, f32) + lds1(b_hh, 128 + c, f32);
    const float bin_ = lds1(b_ih, 256 + c, f32);
    const float bhn  = lds1(b_hh, 256 + c, f32);

    const int stride = (int)(gridDim.x * 4) >> 3;   // row-wave count per jt
    int rb = gw >> 3;
    if (rb >= MBLK) return;

    s16x8 S0[4], S1[4];
    float4 H0[8], H1[8];

    LOAD_A(S0, H0, rb);
    int nxt = rb + stride;
    while (true) {
        if (nxt < MBLK) LOAD_A(S1, H1, nxt);    // prefetch depth 1
        COMPUTE(S0, H0, rb);
        rb = nxt; nxt += stride;
        if (rb >= MBLK) break;
        if (nxt < MBLK) LOAD_A(S0, H0, nxt);
        COMPUTE(S1, H1, rb);
        rb = nxt; nxt += stride;
        if (rb >= MBLK) break;
    }
}

// ---------------------------------------------------------------------------
// GRU safe path (workspace too small): unchanged.
// ---------------------------------------------------------------------------
__global__ __launch_bounds__(512, 2) void gru_safe(
    const u16* __restrict__ spatial, const void* __restrict__ h_prev,
    const void* __restrict__ W_ih, const void* __restrict__ W_hh,
    const void* __restrict__ b_ih, const void* __restrict__ b_hh,
    void* __restrict__ out)
{
    const int f32  = wave_sniff(h_prev);
    const int lane = threadIdx.x & 63;
    const int jt   = threadIdx.x >> 6;
    const int n16  = lane & 15;
    const int quad = lane >> 4;
    const int c    = jt * 16 + n16;
    const int kob  = quad * 8;

    s16x8 Bir[4], Biz[4], Bin[4], Bhr[4], Bhz[4], Bhn[4];
#pragma unroll
    for (int kt = 0; kt < 4; kt++) {
        const int ko = kt * 32 + kob;
        Bir[kt] = ldfrag(W_ih, (size_t)(c)       * HID + ko, f32);
        Biz[kt] = ldfrag(W_ih, (size_t)(128 + c) * HID + ko, f32);
        Bin[kt] = ldfrag(W_ih, (size_t)(256 + c) * HID + ko, f32);
        Bhr[kt] = ldfrag(W_hh, (size_t)(c)       * HID + ko, f32);
        Bhz[kt] = ldfrag(W_hh, (size_t)(128 + c) * HID + ko, f32);
        Bhn[kt] = ldfrag(W_hh, (size_t)(256 + c) * HID + ko, f32);
    }
    const float br   = lds1(b_ih, c, f32)       + lds1(b_hh, c, f32);
    const float bz   = lds1(b_ih, 128 + c, f32) + lds1(b_hh, 128 + c, f32);
    const float bin_ = lds1(b_ih, 256 + c, f32);
    const float bhn  = lds1(b_hh, 256 + c, f32);

    for (int rb = blockIdx.x; rb < MBLK; rb += gridDim.x) {
        const size_t ar = (size_t)(rb * 16 + n16) * HID + kob;
        s16x8 As[4], Ah[4];
#pragma unroll
        for (int kt = 0; kt < 4; kt++) {
            As[kt] = *(const s16x8*)&spatial[ar + kt * 32];
            Ah[kt] = ldfrag(h_prev, ar + kt * 32, f32);
        }

        f32x4 air = {0,0,0,0}, aiz = {0,0,0,0}, ain = {0,0,0,0};
        f32x4 ahr = {0,0,0,0}, ahz = {0,0,0,0}, ahn = {0,0,0,0};
#pragma unroll
        for (int kt = 0; kt < 4; kt++) {
            air = __builtin_amdgcn_mfma_f32_16x16x32_bf16(As[kt], Bir[kt], air, 0, 0, 0);
            ahr = __builtin_amdgcn_mfma_f32_16x16x32_bf16(Ah[kt], Bhr[kt], ahr, 0, 0, 0);
            aiz = __builtin_amdgcn_mfma_f32_16x16x32_bf16(As[kt], Biz[kt], aiz, 0, 0, 0);
            ahz = __builtin_amdgcn_mfma_f32_16x16x32_bf16(Ah[kt], Bhz[kt], ahz, 0, 0, 0);
            ain = __builtin_amdgcn_mfma_f32_16x16x32_bf16(As[kt], Bin[kt], ain, 0, 0, 0);
            ahn = __builtin_amdgcn_mfma_f32_16x16x32_bf16(Ah[kt], Bhn[kt], ahn, 0, 0, 0);
        }

        __syncthreads();   // all spatial reads of rows rb complete before writes

        const int row0 = rb * 16 + quad * 4;
#pragma unroll
        for (int reg = 0; reg < 4; reg++) {
            const size_t o = (size_t)(row0 + reg) * HID + c;
            const float r  = sigm(air[reg] + ahr[reg] + br);
            const float z  = sigm(aiz[reg] + ahz[reg] + bz);
            const float nn = tanh_fast(ain[reg] + bin_ + r * (ahn[reg] + bhn));
            const float hp = lds1(h_prev, o, f32);
            st1(out, o, f32, (1.0f - z) * nn + z * hp);
        }
    }
}

extern "C" void kernel_launch(void* const* d_in, const int* in_sizes, int n_in,
                              void* d_out, int out_size, void* d_ws, size_t ws_size,
                              hipStream_t stream) {
    const void* x      = d_in[0];
    const void* adj    = d_in[1];
    const void* h_prev = d_in[2];
    const void* W_gcn  = d_in[3];
    const void* b_gcn  = d_in[4];
    const void* W_ih   = d_in[5];
    const void* W_hh   = d_in[6];
    const void* b_ih   = d_in[7];
    const void* b_hh   = d_in[8];

    const size_t need   = (size_t)MROWS * HID * sizeof(u16);   // 92 MB bf16 spatial
    const size_t wbytes = (size_t)WELEM * sizeof(u16);         // 96 KB per matrix
    const bool have_ws = (ws_size >= need);
    const bool have_w  = (ws_size >= need + 2 * wbytes);

    u16* spatial = have_ws ? (u16*)d_ws : (u16*)d_out;
    u16* wih_b   = have_w ? (u16*)((char*)d_ws + need) : nullptr;
    u16* whh_b   = have_w ? (u16*)((char*)d_ws + need + wbytes) : nullptr;

    gcn_kernel<<<GCN_BLOCKS + (have_w ? PREP_BLKS : 0), 256, 0, stream>>>(
        x, adj, W_gcn, b_gcn, spatial, W_ih, W_hh, wih_b, whh_b);

    if (have_w)
        gru_fast<<<2048, 256, 0, stream>>>(spatial, h_prev, wih_b, whh_b,
                                           b_ih, b_hh, d_out);
    else
        gru_safe<<<2048, 512, 0, stream>>>(spatial, h_prev, W_ih, W_hh,
                                           b_ih, b_hh, d_out);
}